// Round 4
// baseline (1723.825 us; speedup 1.0000x reference)
//
#include <hip/hip_runtime.h>

typedef unsigned int uint_t;
typedef unsigned short ushort_t;
typedef _Float16 h2 __attribute__((ext_vector_type(2)));
typedef _Float16 f16x8 __attribute__((ext_vector_type(8)));
typedef float f32x4 __attribute__((ext_vector_type(4)));

#define NPTS 1024
#define DIM  128
#define NH2  64

__device__ __forceinline__ float dot2f(uint_t a, uint_t b, float c) {
#if __has_builtin(__builtin_amdgcn_fdot2)
    return __builtin_amdgcn_fdot2(__builtin_bit_cast(h2, a),
                                  __builtin_bit_cast(h2, b), c, false);
#else
    h2 ha = __builtin_bit_cast(h2, a);
    h2 hb = __builtin_bit_cast(h2, b);
    c += (float)ha[0] * (float)hb[0];
    c += (float)ha[1] * (float)hb[1];
    return c;
#endif
}

__device__ __forceinline__ uint_t umin_u(uint_t a, uint_t b) { return a < b ? a : b; }
__device__ __forceinline__ uint_t pk_min_u16(uint_t a, uint_t b) {
    uint_t d; asm("v_pk_min_u16 %0, %1, %2" : "=v"(d) : "v"(a), "v"(b)); return d;
}
__device__ __forceinline__ uint_t pk_max_u16(uint_t a, uint_t b) {
    uint_t d; asm("v_pk_max_u16 %0, %1, %2" : "=v"(d) : "v"(a), "v"(b)); return d;
}

#define DPP_UMIN(x, ctrl)                                                       \
    x = umin_u(x, (uint_t)__builtin_amdgcn_update_dpp((int)(x), (int)(x),       \
                                                      (ctrl), 0xf, 0xf, false))

// ============================ K0: prep ======================================
// fp32 -> fp16 points + fp32 norms (of the quantized coords).
// 16 threads per point-row; block = 16 rows.
__global__ __launch_bounds__(256)
void prep_kernel(const float* __restrict__ reps, ushort_t* __restrict__ P16,
                 float* __restrict__ norms) {
    const int t   = threadIdx.x;
    const int row = blockIdx.x * 16 + (t >> 4);   // s*1024 + p
    const int kx  = (t & 15) * 8;
    const float* src = reps + (size_t)row * DIM + kx;
    float4 v0 = *(const float4*)src;
    float4 v1 = *(const float4*)(src + 4);
    _Float16 h[8] = {(_Float16)v0.x, (_Float16)v0.y, (_Float16)v0.z, (_Float16)v0.w,
                     (_Float16)v1.x, (_Float16)v1.y, (_Float16)v1.z, (_Float16)v1.w};
    float nrm = 0.f;
    uint_t pk[4];
#pragma unroll
    for (int i = 0; i < 4; ++i) {
        float a = (float)h[2 * i], b = (float)h[2 * i + 1];
        nrm += a * a + b * b;
        pk[i] = (uint_t)__builtin_bit_cast(ushort_t, h[2 * i]) |
                ((uint_t)__builtin_bit_cast(ushort_t, h[2 * i + 1]) << 16);
    }
    *(uint4*)(P16 + (size_t)row * DIM + kx) = make_uint4(pk[0], pk[1], pk[2], pk[3]);
#pragma unroll
    for (int m = 1; m <= 8; m <<= 1) nrm += __shfl_xor(nrm, m, 16);
    if ((t & 15) == 0) norms[row] = nrm;
}

// ============================ K1: Gram -> D ================================
// One block per (sample, 128x128 tile). d2[i][j] = n_i + n_j - 2*G[i][j],
// stored as u16: fp16 bits rounded to 12 and low 4 bits = (j & 15) slot tag.
// XOR-swizzled LDS (16B units): unit' = unit ^ (row & 15) -> 2-way max (free).
__device__ __forceinline__ int swz(int row, int seg) {
    return (row << 7) + (((seg ^ row) & 15) << 3);   // u16 index
}

__global__ __launch_bounds__(256, 2)
void gram_kernel(const ushort_t* __restrict__ P16, const float* __restrict__ norms,
                 ushort_t* __restrict__ D16) {
    __shared__ ushort_t At[128 * 128];
    __shared__ ushort_t Bt[128 * 128];
    const int bid = blockIdx.x;
    const int s  = bid >> 6, tile = bid & 63, ti = tile >> 3, tj = tile & 7;
    const int t  = threadIdx.x, lane = t & 63, w = t >> 6;

    const ushort_t* Pa = P16 + (((size_t)s * NPTS + ti * 128) << 7);
    const ushort_t* Pb = P16 + (((size_t)s * NPTS + tj * 128) << 7);
#pragma unroll
    for (int i = 0; i < 8; ++i) {
        int c = t + i * 256, row = c >> 4, seg = c & 15;
        uint4 va = *(const uint4*)(Pa + (row << 7) + seg * 8);
        uint4 vb = *(const uint4*)(Pb + (row << 7) + seg * 8);
        *(uint4*)&At[swz(row, seg)] = va;
        *(uint4*)&Bt[swz(row, seg)] = vb;
    }
    __syncthreads();

    f32x4 acc[2][8] = {};
    const int mrow = lane & 15;
    const int lg   = lane >> 4;
#pragma unroll
    for (int q = 0; q < 4; ++q) {
        const int seg = q * 4 + lg;   // 16B unit index along K
        f16x8 a0 = *(const f16x8*)&At[swz(w * 32 + mrow, seg)];
        f16x8 a1 = *(const f16x8*)&At[swz(w * 32 + 16 + mrow, seg)];
#pragma unroll
        for (int nt = 0; nt < 8; ++nt) {
            f16x8 b = *(const f16x8*)&Bt[swz(nt * 16 + mrow, seg)];
            acc[0][nt] = __builtin_amdgcn_mfma_f32_16x16x32_f16(a0, b, acc[0][nt], 0, 0, 0);
            acc[1][nt] = __builtin_amdgcn_mfma_f32_16x16x32_f16(a1, b, acc[1][nt], 0, 0, 0);
        }
    }

    // epilogue: C/D layout col = lane&15, row = (lane>>4)*4 + reg
    const int cj = lane & 15;
    const int r4 = (lane >> 4) * 4;
    const float* nrmS = norms + (size_t)s * NPTS;
    float na[2][4], nb[8];
#pragma unroll
    for (int mt = 0; mt < 2; ++mt)
#pragma unroll
        for (int r = 0; r < 4; ++r)
            na[mt][r] = nrmS[ti * 128 + w * 32 + mt * 16 + r4 + r];
#pragma unroll
    for (int nt = 0; nt < 8; ++nt) nb[nt] = nrmS[tj * 128 + nt * 16 + cj];

    ushort_t* Ds = D16 + ((size_t)s << 20);
#pragma unroll
    for (int mt = 0; mt < 2; ++mt)
#pragma unroll
        for (int nt = 0; nt < 8; ++nt) {
            const int gj = tj * 128 + nt * 16 + cj;
#pragma unroll
            for (int r = 0; r < 4; ++r) {
                const int gi = ti * 128 + w * 32 + mt * 16 + r4 + r;
                float d2 = fmaxf(na[mt][r] + nb[nt] - 2.f * acc[mt][nt][r], 0.f);
                uint_t u = (uint_t)__builtin_bit_cast(ushort_t, (_Float16)d2);
                u = ((u + 8u) & 0xFFF0u) | (uint_t)(gj & 15);   // 12-bit round + slot tag
                Ds[((size_t)gi << 10) + gj] = (ushort_t)u;
            }
        }
}

// ============================ K2: single-wave Prim ==========================
// One 64-lane wave per sample. Lane owns points p = lane*16 + k, k=0..15,
// min-keys held as 8 packed u16 regs (value = d12<<4 | slot). No barriers/LDS.
__global__ __launch_bounds__(64, 1)
void prim_rows_kernel(const ushort_t* __restrict__ D16, float* __restrict__ out,
                      float scale) {
    const int s    = blockIdx.x;
    const int lane = threadIdx.x;
    const ushort_t* Drow = D16 + ((size_t)s << 20);

    uint_t md[8], po[8];
#pragma unroll
    for (int m = 0; m < 8; ++m) { md[m] = 0xFFFFFFFFu; po[m] = 0u; }
    const uint_t lane16 = (uint_t)lane << 4;
    uint_t p   = 0;
    float  acc = 0.f;

    for (int it = 0; it < NPTS - 1; ++it) {
        // (1) issue row-p load: lane covers its own 16 columns (32 B)
        const uint4* rp = (const uint4*)(Drow + ((size_t)p << 10));
        uint4 r0 = rp[2 * lane];
        uint4 r1 = rp[2 * lane + 1];

        // (2) poison point p (set its slot to 0xFFFF in md and po) while load flies
        const bool  win = (p >> 4) == (uint_t)lane;
        const uint_t sl = p & 15u;
#pragma unroll
        for (int m = 0; m < 8; ++m) {
            uint_t h = (win && sl == 2u * m)      ? 0x0000FFFFu
                     : (win && sl == 2u * m + 1u) ? 0xFFFF0000u : 0u;
            md[m] |= h; po[m] |= h;
        }

        // (3) min-update: md = min(md, max(row, poison))
        md[0] = pk_min_u16(md[0], pk_max_u16(r0.x, po[0]));
        md[1] = pk_min_u16(md[1], pk_max_u16(r0.y, po[1]));
        md[2] = pk_min_u16(md[2], pk_max_u16(r0.z, po[2]));
        md[3] = pk_min_u16(md[3], pk_max_u16(r0.w, po[3]));
        md[4] = pk_min_u16(md[4], pk_max_u16(r1.x, po[4]));
        md[5] = pk_min_u16(md[5], pk_max_u16(r1.y, po[5]));
        md[6] = pk_min_u16(md[6], pk_max_u16(r1.z, po[6]));
        md[7] = pk_min_u16(md[7], pk_max_u16(r1.w, po[7]));

        // (4) per-lane min over 16 slots (slot id rides in low 4 bits)
        uint_t t0 = pk_min_u16(pk_min_u16(md[0], md[1]), pk_min_u16(md[2], md[3]));
        uint_t t1 = pk_min_u16(pk_min_u16(md[4], md[5]), pk_min_u16(md[6], md[7]));
        uint_t tt = pk_min_u16(t0, t1);
        uint_t v16 = umin_u(tt & 0xFFFFu, tt >> 16);

        // (5) wave argmin on key = (d12, lane, slot)
        uint_t key = ((v16 & 0xFFF0u) << 6) | lane16 | (v16 & 15u);
        DPP_UMIN(key, 0x111);
        DPP_UMIN(key, 0x112);
        DPP_UMIN(key, 0x114);
        DPP_UMIN(key, 0x118);
        DPP_UMIN(key, 0x142);
        DPP_UMIN(key, 0x143);
        uint_t g = (uint_t)__builtin_amdgcn_readlane((int)key, 63);

        p = g & 1023u;                                   // next frontier point
        float d2 = (float)__builtin_bit_cast(_Float16, (ushort_t)((g >> 6) & 0xFFF0u));
        acc += sqrtf(d2);
    }

    if (lane == 0) atomicAdd(out, acc * scale);
}

// ===================== fallback (R3, correct but slow) ======================
#define NTHR 256
#define NWAVE 4
#define PPT  4
__global__ __launch_bounds__(NTHR, 1)
void prim_mst_kernel(const float* __restrict__ reps, float* __restrict__ out,
                     float scale) {
    const int s = blockIdx.x, t = threadIdx.x, lane = t & 63, wave = t >> 6;
    __shared__ uint4  sc[NH2 / 4];
    __shared__ float  snrm;
    __shared__ __align__(16) uint_t warr[NWAVE];
    __shared__ float  facc[NWAVE];
    uint_t cx[PPT][NH2]; float nrm[PPT], mind[PPT];
#pragma unroll
    for (int p = 0; p < PPT; ++p) {
        const float4* src = (const float4*)(reps + (size_t)s * (NPTS * DIM) +
                                            (size_t)(p * NTHR + t) * DIM);
        float n = 0.f;
#pragma unroll
        for (int k = 0; k < 32; ++k) {
            float4 v = src[k];
            h2 a; a[0] = (_Float16)v.x; a[1] = (_Float16)v.y;
            h2 b; b[0] = (_Float16)v.z; b[1] = (_Float16)v.w;
            cx[p][2 * k] = __builtin_bit_cast(uint_t, a);
            cx[p][2 * k + 1] = __builtin_bit_cast(uint_t, b);
            n = dot2f(cx[p][2 * k], cx[p][2 * k], n);
            n = dot2f(cx[p][2 * k + 1], cx[p][2 * k + 1], n);
        }
        nrm[p] = n; mind[p] = 3.0e38f;
    }
    uint_t vis = 0;
    if (t == 0) {
#pragma unroll
        for (int k = 0; k < NH2 / 4; ++k)
            sc[k] = make_uint4(cx[0][4 * k], cx[0][4 * k + 1], cx[0][4 * k + 2], cx[0][4 * k + 3]);
        snrm = nrm[0]; vis = 1;
    }
    __syncthreads();
    float acc = 0.f;
    for (int it = 0; it < NPTS - 1; ++it) {
        const float bn = snrm;
        float e0[PPT], e1[PPT];
#pragma unroll
        for (int p = 0; p < PPT; ++p) { e0[p] = 0.f; e1[p] = 0.f; }
#pragma unroll
        for (int k = 0; k < NH2 / 4; ++k) {
            uint4 q = sc[k];
#pragma unroll
            for (int p = 0; p < PPT; ++p) {
                e0[p] = dot2f(cx[p][4 * k + 0], q.x, e0[p]);
                e1[p] = dot2f(cx[p][4 * k + 1], q.y, e1[p]);
                e0[p] = dot2f(cx[p][4 * k + 2], q.z, e0[p]);
                e1[p] = dot2f(cx[p][4 * k + 3], q.w, e1[p]);
            }
        }
        uint_t key = 0xFFFFFFFFu;
#pragma unroll
        for (int p = 0; p < PPT; ++p) {
            float d2 = fmaxf(bn + nrm[p] - 2.f * (e0[p] + e1[p]), 0.f);
            mind[p] = fminf(mind[p], d2);
            uint_t kp = ((vis >> p) & 1u) ? 0xFFFFFFFFu
                      : ((__float_as_uint(mind[p]) & 0xFFFFFC00u) | (uint_t)(p * NTHR + t));
            key = umin_u(key, kp);
        }
        DPP_UMIN(key, 0x111); DPP_UMIN(key, 0x112); DPP_UMIN(key, 0x114);
        DPP_UMIN(key, 0x118); DPP_UMIN(key, 0x142); DPP_UMIN(key, 0x143);
        uint_t wkey = (uint_t)__builtin_amdgcn_readlane((int)key, 63);
        if (lane == 0) warr[wave] = wkey;
        __syncthreads();
        uint4 wv = *(const uint4*)warr;
        uint_t g = umin_u(umin_u(wv.x, wv.y), umin_u(wv.z, wv.w));
        const int j = (int)(g & 0x3FFu), jp = j >> 8;
        if ((j & (NTHR - 1)) == t) {
#pragma unroll
            for (int p = 0; p < PPT; ++p)
                if (jp == p) {
#pragma unroll
                    for (int k = 0; k < NH2 / 4; ++k)
                        sc[k] = make_uint4(cx[p][4 * k], cx[p][4 * k + 1],
                                           cx[p][4 * k + 2], cx[p][4 * k + 3]);
                    snrm = nrm[p]; acc += sqrtf(mind[p]);
                }
            vis |= 1u << jp;
        }
        __syncthreads();
    }
#pragma unroll
    for (int m = 32; m >= 1; m >>= 1) acc += __shfl_xor(acc, m, 64);
    if (lane == 0) facc[wave] = acc;
    __syncthreads();
    if (t == 0) atomicAdd(out, (facc[0] + facc[1] + facc[2] + facc[3]) * scale);
}

// ============================ launch ========================================
extern "C" void kernel_launch(void* const* d_in, const int* in_sizes, int n_in,
                              void* d_out, int out_size, void* d_ws, size_t ws_size,
                              hipStream_t stream) {
    const float* reps = (const float*)d_in[0];
    float*       out  = (float*)d_out;
    const int ns = in_sizes[0] / (NPTS * DIM);
    const float scale = 1.0f / ((float)(NPTS - 1) * (float)ns * 2.0f);

    hipMemsetAsync(out, 0, sizeof(float), stream);

    const size_t bytes_D = (size_t)ns << 21;                 // ns * 1024*1024*2
    const size_t bytes_P = (size_t)ns << 18;                 // ns * 1024*128*2
    const size_t bytes_N = (size_t)ns << 12;                 // ns * 1024*4
    if (ws_size >= bytes_D + bytes_P + bytes_N) {
        ushort_t* D16  = (ushort_t*)d_ws;
        ushort_t* P16  = (ushort_t*)((char*)d_ws + bytes_D);
        float*    nrms = (float*)((char*)d_ws + bytes_D + bytes_P);
        prep_kernel<<<dim3(ns * 64), dim3(256), 0, stream>>>(reps, P16, nrms);
        gram_kernel<<<dim3(ns * 64), dim3(256), 0, stream>>>(P16, nrms, D16);
        prim_rows_kernel<<<dim3(ns), dim3(64), 0, stream>>>(D16, out, scale);
    } else {
        prim_mst_kernel<<<dim3(ns), dim3(NTHR), 0, stream>>>(reps, out, scale);
    }
}

// Round 5
// 671.112 us; speedup vs baseline: 2.5686x; 2.5686x over previous
//
#include <hip/hip_runtime.h>

typedef unsigned int uint_t;
typedef unsigned short ushort_t;
typedef unsigned char uchar_t;
typedef _Float16 h2 __attribute__((ext_vector_type(2)));
typedef _Float16 f16x8 __attribute__((ext_vector_type(8)));
typedef float f32x4 __attribute__((ext_vector_type(4)));

#define NPTS 1024
#define DIM  128
#define NH2  64

__device__ __forceinline__ float dot2f(uint_t a, uint_t b, float c) {
#if __has_builtin(__builtin_amdgcn_fdot2)
    return __builtin_amdgcn_fdot2(__builtin_bit_cast(h2, a),
                                  __builtin_bit_cast(h2, b), c, false);
#else
    h2 ha = __builtin_bit_cast(h2, a);
    h2 hb = __builtin_bit_cast(h2, b);
    c += (float)ha[0] * (float)hb[0];
    c += (float)ha[1] * (float)hb[1];
    return c;
#endif
}

__device__ __forceinline__ uint_t umin_u(uint_t a, uint_t b) { return a < b ? a : b; }
__device__ __forceinline__ uint_t pk_min_u16(uint_t a, uint_t b) {
    uint_t d; asm("v_pk_min_u16 %0, %1, %2" : "=v"(d) : "v"(a), "v"(b)); return d;
}
__device__ __forceinline__ uint_t pk_max_u16(uint_t a, uint_t b) {
    uint_t d; asm("v_pk_max_u16 %0, %1, %2" : "=v"(d) : "v"(a), "v"(b)); return d;
}

#define DPP_UMIN(x, ctrl)                                                       \
    x = umin_u(x, (uint_t)__builtin_amdgcn_update_dpp((int)(x), (int)(x),       \
                                                      (ctrl), 0xf, 0xf, false))

// ===================== K0: norms of fp16-quantized rows =====================
// 16 threads per point-row; block = 16 rows. Must quantize EXACTLY like gram.
__global__ __launch_bounds__(256)
void norms_kernel(const float* __restrict__ reps, float* __restrict__ norms) {
    const int t   = threadIdx.x;
    const int row = blockIdx.x * 16 + (t >> 4);   // global: s*1024 + p
    const int kx  = (t & 15) * 8;
    const float* src = reps + (size_t)row * DIM + kx;
    float4 v0 = *(const float4*)src;
    float4 v1 = *(const float4*)(src + 4);
    float nrm = 0.f;
    {
        _Float16 h[8] = {(_Float16)v0.x, (_Float16)v0.y, (_Float16)v0.z, (_Float16)v0.w,
                         (_Float16)v1.x, (_Float16)v1.y, (_Float16)v1.z, (_Float16)v1.w};
#pragma unroll
        for (int i = 0; i < 8; ++i) { float a = (float)h[i]; nrm += a * a; }
    }
#pragma unroll
    for (int m = 1; m <= 8; m <<= 1) nrm += __shfl_xor(nrm, m, 16);
    if ((t & 15) == 0) norms[row] = nrm;
}

// ===================== K1: Gram -> u8 distance matrix =======================
// One block per (chunk-sample, 128x128 tile). d2 = n_i + n_j - 2*G, stored as
// q = clamp(round(d2/2), 0, 255)  (1 byte). XOR-swizzled fp16 LDS tiles.
__device__ __forceinline__ int swz(int row, int seg) {
    return (row << 7) + (((seg ^ row) & 15) << 3);   // u16 index
}
__device__ __forceinline__ uint_t packh2(float a, float b) {
    h2 p; p[0] = (_Float16)a; p[1] = (_Float16)b;
    return __builtin_bit_cast(uint_t, p);
}

__global__ __launch_bounds__(256, 2)
void gram_kernel(const float* __restrict__ reps, const float* __restrict__ norms,
                 uchar_t* __restrict__ D8, int s_base) {
    __shared__ ushort_t At[128 * 128];
    __shared__ ushort_t Bt[128 * 128];
    const int bid  = blockIdx.x;
    const int sl   = bid >> 6, tile = bid & 63, ti = tile >> 3, tj = tile & 7;
    const int s    = s_base + sl;
    const int t    = threadIdx.x, lane = t & 63, w = t >> 6;

    const float* Pa = reps + ((size_t)s * NPTS + (size_t)ti * 128) * DIM;
    const float* Pb = reps + ((size_t)s * NPTS + (size_t)tj * 128) * DIM;
#pragma unroll
    for (int i = 0; i < 8; ++i) {
        int c = t + i * 256, row = c >> 4, seg = c & 15;
        const float* pa = Pa + row * DIM + seg * 8;
        const float* pb = Pb + row * DIM + seg * 8;
        float4 a0 = *(const float4*)pa, a1 = *(const float4*)(pa + 4);
        float4 b0 = *(const float4*)pb, b1 = *(const float4*)(pb + 4);
        *(uint4*)&At[swz(row, seg)] = make_uint4(packh2(a0.x, a0.y), packh2(a0.z, a0.w),
                                                 packh2(a1.x, a1.y), packh2(a1.z, a1.w));
        *(uint4*)&Bt[swz(row, seg)] = make_uint4(packh2(b0.x, b0.y), packh2(b0.z, b0.w),
                                                 packh2(b1.x, b1.y), packh2(b1.z, b1.w));
    }
    __syncthreads();

    f32x4 acc[2][8] = {};
    const int mrow = lane & 15;
    const int lg   = lane >> 4;
#pragma unroll
    for (int q = 0; q < 4; ++q) {
        const int seg = q * 4 + lg;   // 8-fp16 unit index along K
        f16x8 a0 = *(const f16x8*)&At[swz(w * 32 + mrow, seg)];
        f16x8 a1 = *(const f16x8*)&At[swz(w * 32 + 16 + mrow, seg)];
#pragma unroll
        for (int nt = 0; nt < 8; ++nt) {
            f16x8 b = *(const f16x8*)&Bt[swz(nt * 16 + mrow, seg)];
            acc[0][nt] = __builtin_amdgcn_mfma_f32_16x16x32_f16(a0, b, acc[0][nt], 0, 0, 0);
            acc[1][nt] = __builtin_amdgcn_mfma_f32_16x16x32_f16(a1, b, acc[1][nt], 0, 0, 0);
        }
    }

    // epilogue: C/D layout col = lane&15, row = (lane>>4)*4 + reg
    const int cj = lane & 15;
    const int r4 = (lane >> 4) * 4;
    const float* nrmS = norms + (size_t)s * NPTS;
    float na[2][4], nb[8];
#pragma unroll
    for (int mt = 0; mt < 2; ++mt)
#pragma unroll
        for (int r = 0; r < 4; ++r)
            na[mt][r] = nrmS[ti * 128 + w * 32 + mt * 16 + r4 + r];
#pragma unroll
    for (int nt = 0; nt < 8; ++nt) nb[nt] = nrmS[tj * 128 + nt * 16 + cj];

    uchar_t* Ds = D8 + ((size_t)sl << 20);
#pragma unroll
    for (int mt = 0; mt < 2; ++mt)
#pragma unroll
        for (int nt = 0; nt < 8; ++nt) {
            const int gj = tj * 128 + nt * 16 + cj;
#pragma unroll
            for (int r = 0; r < 4; ++r) {
                const int gi = ti * 128 + w * 32 + mt * 16 + r4 + r;
                float d2 = fmaxf(na[mt][r] + nb[nt] - 2.f * acc[mt][nt][r], 0.f);
                uint_t q = (uint_t)(d2 * 0.5f + 0.5f);
                q = q > 255u ? 255u : q;
                Ds[((size_t)gi << 10) + gj] = (uchar_t)q;
            }
        }
}

// ===================== K2: single-wave Prim over u8 rows ====================
// One 64-lane wave per chunk-sample. Lane owns points p = lane*16+k (k=0..15),
// min-keys as 8 packed u16 regs (value = q<<8 | slot). No barriers, no LDS.
__device__ __forceinline__ uint_t bpair(uint_t x, int lo, uint_t slots) {
    // bytes lo, lo+1 of x -> low u16 = (b_lo<<8)|slot_lo, high = (b_{lo+1}<<8)|slot_hi
    return (((x >> (8 * lo)) & 0xFFu) << 8) |
           (((x >> (8 * lo + 8)) & 0xFFu) << 24) | slots;
}

__global__ __launch_bounds__(64, 1)
void prim_u8_kernel(const uchar_t* __restrict__ D8, float* __restrict__ out,
                    float scale) {
    const int sl   = blockIdx.x;
    const int lane = threadIdx.x;
    const uchar_t* Dbase = D8 + ((size_t)sl << 20);

    uint_t md[8], po[8];
#pragma unroll
    for (int m = 0; m < 8; ++m) { md[m] = 0xFFFFFFFFu; po[m] = 0u; }
    const uint_t lane16 = (uint_t)lane << 4;
    uint_t p   = 0;
    float  acc = 0.f;

    for (int it = 0; it < NPTS - 1; ++it) {
        // (1) issue row-p load: lane covers its own 16 columns (16 B)
        const uint4* rp = (const uint4*)(Dbase + ((size_t)p << 10));
        uint4 r = rp[lane];

        // (2) poison point p while the load flies (sticky via po)
        const bool  win = (p >> 4) == (uint_t)lane;
        const uint_t s4 = p & 15u;
#pragma unroll
        for (int m = 0; m < 8; ++m) {
            uint_t h = (win && s4 == 2u * m)      ? 0x0000FFFFu
                     : (win && s4 == 2u * m + 1u) ? 0xFFFF0000u : 0u;
            md[m] |= h; po[m] |= h;
        }

        // (3) unpack bytes -> (q<<8|slot) u16 pairs; md = min(md, max(row, po))
        md[0] = pk_min_u16(md[0], pk_max_u16(bpair(r.x, 0, 0x00010000u), po[0]));
        md[1] = pk_min_u16(md[1], pk_max_u16(bpair(r.x, 2, 0x00030002u), po[1]));
        md[2] = pk_min_u16(md[2], pk_max_u16(bpair(r.y, 0, 0x00050004u), po[2]));
        md[3] = pk_min_u16(md[3], pk_max_u16(bpair(r.y, 2, 0x00070006u), po[3]));
        md[4] = pk_min_u16(md[4], pk_max_u16(bpair(r.z, 0, 0x00090008u), po[4]));
        md[5] = pk_min_u16(md[5], pk_max_u16(bpair(r.z, 2, 0x000B000Au), po[5]));
        md[6] = pk_min_u16(md[6], pk_max_u16(bpair(r.w, 0, 0x000D000Cu), po[6]));
        md[7] = pk_min_u16(md[7], pk_max_u16(bpair(r.w, 2, 0x000F000Eu), po[7]));

        // (4) per-lane min over 16 slots (slot id rides in low 4 bits)
        uint_t t0 = pk_min_u16(pk_min_u16(md[0], md[1]), pk_min_u16(md[2], md[3]));
        uint_t t1 = pk_min_u16(pk_min_u16(md[4], md[5]), pk_min_u16(md[6], md[7]));
        uint_t tt = pk_min_u16(t0, t1);
        uint_t v16 = umin_u(tt & 0xFFFFu, tt >> 16);

        // (5) wave argmin on key = (q, lane, slot)
        uint_t key = ((v16 & 0xFF00u) << 2) | lane16 | (v16 & 15u);
        DPP_UMIN(key, 0x111);
        DPP_UMIN(key, 0x112);
        DPP_UMIN(key, 0x114);
        DPP_UMIN(key, 0x118);
        DPP_UMIN(key, 0x142);
        DPP_UMIN(key, 0x143);
        uint_t g = (uint_t)__builtin_amdgcn_readlane((int)key, 63);

        p = g & 1023u;                       // next frontier point
        acc += sqrtf(2.0f * (float)(g >> 10));
    }

    if (lane == 0) atomicAdd(out, acc * scale);
}

// ===================== fallback (R3, correct but slow) ======================
#define NTHR 256
#define NWAVE 4
#define PPT  4
__global__ __launch_bounds__(NTHR, 1)
void prim_mst_kernel(const float* __restrict__ reps, float* __restrict__ out,
                     float scale) {
    const int s = blockIdx.x, t = threadIdx.x, lane = t & 63, wave = t >> 6;
    __shared__ uint4  sc[NH2 / 4];
    __shared__ float  snrm;
    __shared__ __align__(16) uint_t warr[NWAVE];
    __shared__ float  facc[NWAVE];
    uint_t cx[PPT][NH2]; float nrm[PPT], mind[PPT];
#pragma unroll
    for (int p = 0; p < PPT; ++p) {
        const float4* src = (const float4*)(reps + (size_t)s * (NPTS * DIM) +
                                            (size_t)(p * NTHR + t) * DIM);
        float n = 0.f;
#pragma unroll
        for (int k = 0; k < 32; ++k) {
            float4 v = src[k];
            h2 a; a[0] = (_Float16)v.x; a[1] = (_Float16)v.y;
            h2 b; b[0] = (_Float16)v.z; b[1] = (_Float16)v.w;
            cx[p][2 * k] = __builtin_bit_cast(uint_t, a);
            cx[p][2 * k + 1] = __builtin_bit_cast(uint_t, b);
            n = dot2f(cx[p][2 * k], cx[p][2 * k], n);
            n = dot2f(cx[p][2 * k + 1], cx[p][2 * k + 1], n);
        }
        nrm[p] = n; mind[p] = 3.0e38f;
    }
    uint_t vis = 0;
    if (t == 0) {
#pragma unroll
        for (int k = 0; k < NH2 / 4; ++k)
            sc[k] = make_uint4(cx[0][4 * k], cx[0][4 * k + 1], cx[0][4 * k + 2], cx[0][4 * k + 3]);
        snrm = nrm[0]; vis = 1;
    }
    __syncthreads();
    float acc = 0.f;
    for (int it = 0; it < NPTS - 1; ++it) {
        const float bn = snrm;
        float e0[PPT], e1[PPT];
#pragma unroll
        for (int p = 0; p < PPT; ++p) { e0[p] = 0.f; e1[p] = 0.f; }
#pragma unroll
        for (int k = 0; k < NH2 / 4; ++k) {
            uint4 q = sc[k];
#pragma unroll
            for (int p = 0; p < PPT; ++p) {
                e0[p] = dot2f(cx[p][4 * k + 0], q.x, e0[p]);
                e1[p] = dot2f(cx[p][4 * k + 1], q.y, e1[p]);
                e0[p] = dot2f(cx[p][4 * k + 2], q.z, e0[p]);
                e1[p] = dot2f(cx[p][4 * k + 3], q.w, e1[p]);
            }
        }
        uint_t key = 0xFFFFFFFFu;
#pragma unroll
        for (int p = 0; p < PPT; ++p) {
            float d2 = fmaxf(bn + nrm[p] - 2.f * (e0[p] + e1[p]), 0.f);
            mind[p] = fminf(mind[p], d2);
            uint_t kp = ((vis >> p) & 1u) ? 0xFFFFFFFFu
                      : ((__float_as_uint(mind[p]) & 0xFFFFFC00u) | (uint_t)(p * NTHR + t));
            key = umin_u(key, kp);
        }
        DPP_UMIN(key, 0x111); DPP_UMIN(key, 0x112); DPP_UMIN(key, 0x114);
        DPP_UMIN(key, 0x118); DPP_UMIN(key, 0x142); DPP_UMIN(key, 0x143);
        uint_t wkey = (uint_t)__builtin_amdgcn_readlane((int)key, 63);
        if (lane == 0) warr[wave] = wkey;
        __syncthreads();
        uint4 wv = *(const uint4*)warr;
        uint_t g = umin_u(umin_u(wv.x, wv.y), umin_u(wv.z, wv.w));
        const int j = (int)(g & 0x3FFu), jp = j >> 8;
        if ((j & (NTHR - 1)) == t) {
#pragma unroll
            for (int p = 0; p < PPT; ++p)
                if (jp == p) {
#pragma unroll
                    for (int k = 0; k < NH2 / 4; ++k)
                        sc[k] = make_uint4(cx[p][4 * k], cx[p][4 * k + 1],
                                           cx[p][4 * k + 2], cx[p][4 * k + 3]);
                    snrm = nrm[p]; acc += sqrtf(mind[p]);
                }
            vis |= 1u << jp;
        }
        __syncthreads();
    }
#pragma unroll
    for (int m = 32; m >= 1; m >>= 1) acc += __shfl_xor(acc, m, 64);
    if (lane == 0) facc[wave] = acc;
    __syncthreads();
    if (t == 0) atomicAdd(out, (facc[0] + facc[1] + facc[2] + facc[3]) * scale);
}

// ============================ launch ========================================
extern "C" void kernel_launch(void* const* d_in, const int* in_sizes, int n_in,
                              void* d_out, int out_size, void* d_ws, size_t ws_size,
                              hipStream_t stream) {
    const float* reps = (const float*)d_in[0];
    float*       out  = (float*)d_out;
    const int ns = in_sizes[0] / (NPTS * DIM);
    const float scale = 1.0f / ((float)(NPTS - 1) * (float)ns * 2.0f);

    hipMemsetAsync(out, 0, sizeof(float), stream);

    // ws layout: [ D8 chunk : nc MB ][ ... ][ norms : ns*4KB at tail ]
    const size_t normsB = (size_t)ns * NPTS * sizeof(float);
    int nc = 0;
    size_t norms_off = 0;
    if (ws_size > normsB + (1u << 20)) {
        norms_off = (ws_size - normsB) & ~(size_t)15;
        nc = (int)(norms_off >> 20);
        if (nc > ns) nc = ns;
    }

    if (nc >= 32) {
        uchar_t* D8    = (uchar_t*)d_ws;
        float*   norms = (float*)((char*)d_ws + norms_off);
        norms_kernel<<<dim3(ns * 64), dim3(256), 0, stream>>>(reps, norms);
        for (int base = 0; base < ns; base += nc) {
            const int n = (ns - base < nc) ? (ns - base) : nc;
            gram_kernel<<<dim3(n * 64), dim3(256), 0, stream>>>(reps, norms, D8, base);
            prim_u8_kernel<<<dim3(n), dim3(64), 0, stream>>>(D8, out, scale);
        }
    } else {
        prim_mst_kernel<<<dim3(ns), dim3(NTHR), 0, stream>>>(reps, out, scale);
    }
}